// Round 2
// baseline (1324.968 us; speedup 1.0000x reference)
//
#include <hip/hip_runtime.h>
#include <cstdio>
#include <cstdint>
#include <cstddef>

#define AS_GLOBAL __attribute__((address_space(1)))
#define AS_LDS    __attribute__((address_space(3)))

typedef __bf16 bf16x8  __attribute__((ext_vector_type(8)));
typedef float  f32x16  __attribute__((ext_vector_type(16)));

constexpr int OUT_F = 4096;
constexpr int IN_F  = 4096;
constexpr int MROWS = 8 * 2048;   // B*S = 16384

// ---------------------------------------------------------------------------
// Kernel 1: dequantize W_q (int32 u8 values, shape [64][262144] row-major)
// into bf16 W[o][i] row-major [4096][4096].
//   flat(Wq) = (o>>6)*2^18 + n,  group n = (o&63)*4096 + i
// ---------------------------------------------------------------------------
__global__ void dequant_w(const int* __restrict__ Wq, const float* __restrict__ scale,
                          const float* __restrict__ zero, __bf16* __restrict__ Wb) {
    int t   = blockIdx.x * blockDim.x + threadIdx.x;
    int idx = t * 4;                       // flat index into W[o][i]
    int o   = idx >> 12;
    int i   = idx & 4095;
    int n   = ((o & 63) << 12) | i;        // group index
    size_t flat = ((size_t)(o >> 6) << 18) + (size_t)n;
    int4   q = *(const int4*)(Wq + flat);
    float4 z = *(const float4*)(zero + n);
    float4 s = *(const float4*)(scale + n);
    __bf16 r[4];
    r[0] = (__bf16)(((float)q.x - z.x) * s.x);
    r[1] = (__bf16)(((float)q.y - z.y) * s.y);
    r[2] = (__bf16)(((float)q.z - z.z) * s.z);
    r[3] = (__bf16)(((float)q.w - z.w) * s.w);
    *(uint2*)(Wb + idx) = *(const uint2*)r;
}

// ---------------------------------------------------------------------------
// Kernel 2: x fp32 -> bf16 (halves GEMM A-panel fetch volume)
// ---------------------------------------------------------------------------
__global__ void convert_x(const float* __restrict__ x, __bf16* __restrict__ xb) {
    size_t t   = (size_t)blockIdx.x * blockDim.x + threadIdx.x;
    size_t idx = t * 8;
    float4 a = *(const float4*)(x + idx);
    float4 b = *(const float4*)(x + idx + 4);
    __bf16 r[8];
    r[0] = (__bf16)a.x; r[1] = (__bf16)a.y; r[2] = (__bf16)a.z; r[3] = (__bf16)a.w;
    r[4] = (__bf16)b.x; r[5] = (__bf16)b.y; r[6] = (__bf16)b.z; r[7] = (__bf16)b.w;
    *(uint4*)(xb + idx) = *(const uint4*)r;
}

// ---------------------------------------------------------------------------
// Kernel 3: C[M][N] = A[M][K] * B[N][K]^T + bias   (bf16 in, fp32 out)
// 128x128 tile, BK=32, 256 threads (4 waves 2x2); each wave computes its
// 64x64 quadrant as 2x2 tiles of mfma_f32_32x32x16_bf16 (2 K-steps / iter).
//
// LDS layout: row-major [128 rows][4 chunks of 16B], but chunk c of row r is
// stored at slot (c ^ (r&3)) — XOR swizzle so 32x32 fragment reads spread
// across all 32 banks (unswizzled, each half-wave hits only 8 banks = 2x).
// global_load_lds writes lane->offset lane*16 (wave-uniform base), so the
// swizzle is applied on the SOURCE address: lane at (r, slot s) fetches
// global chunk s ^ (r&3).
// ---------------------------------------------------------------------------
__device__ __forceinline__ void load16_to_lds(const void* g, void* lds) {
    __builtin_amdgcn_global_load_lds((AS_GLOBAL void*)g, (AS_LDS void*)lds, 16, 0, 0);
}

__global__ __launch_bounds__(256) void gemm_bt_bias(
    const __bf16* __restrict__ A,   // [M][K]
    const __bf16* __restrict__ B,   // [N][K]
    const float*  __restrict__ bias,
    float*        __restrict__ C)   // [M][N]
{
    constexpr int K = IN_F, N = OUT_F;
    constexpr int BKt = 32;
    __shared__ __align__(16) __bf16 sA[128 * BKt];   // 8 KB
    __shared__ __align__(16) __bf16 sB[128 * BKt];   // 8 KB

    const int tid  = threadIdx.x;
    const int lane = tid & 63;
    const int w    = tid >> 6;       // wave 0..3
    const int wr   = w >> 1;         // wave row (0..1)
    const int wc   = w & 1;          // wave col (0..1)
    const int m0   = blockIdx.y * 128;
    const int n0   = blockIdx.x * 128;

    f32x16 acc[2][2] = {};

    // Staging: lane tid covers tile row r0 = tid>>2, LDS slot tid&3.
    // XOR swizzle: fetch global chunk (slot ^ (r0&3)). r0&3 == (tid>>2)&3 for
    // both issues (row+64 preserves mod 4).
    const int r0 = tid >> 2;
    const int cc = (((tid & 3) ^ (r0 & 3))) * 8;   // element offset of fetched chunk
    const __bf16* gA0 = A + (size_t)(m0 + r0) * K + cc;
    const __bf16* gA1 = gA0 + (size_t)64 * K;
    const __bf16* gB0 = B + (size_t)(n0 + r0) * K + cc;
    const __bf16* gB1 = gB0 + (size_t)64 * K;
    // wave-uniform LDS bases: wave w's 64 lanes fill bytes [w*1024, w*1024+1024)
    char* sAb = (char*)sA + w * 1024;
    char* sBb = (char*)sB + w * 1024;

    // Fragment addressing (32x32x16): lane holds op[r = lane&31][k=(lane>>5)*8+j].
    // Within BK=32, kstep s uses chunks {2s, 2s+1}; this lane reads chunk
    // 2s + (lane>>5), at swizzled slot (chunk ^ (row&3)), row&3 == lane&3.
    const int frow = lane & 31;
    const int hs   = lane >> 5;
    const int l3   = lane & 3;
    const int slot0 = hs ^ l3;        // kstep 0
    const int slot1 = slot0 ^ 2;      // kstep 1 (chunk += 2)

    for (int k0 = 0; k0 < K; k0 += BKt) {
        __syncthreads();                       // prev iter's LDS reads done
        load16_to_lds(gA0 + k0, sAb);
        load16_to_lds(gA1 + k0, sAb + 4096);
        load16_to_lds(gB0 + k0, sBb);
        load16_to_lds(gB1 + k0, sBb + 4096);
        __syncthreads();                       // vmcnt drained before barrier

        bf16x8 aF[2][2], bF[2][2];             // [kstep][tile]
#pragma unroll
        for (int mi = 0; mi < 2; ++mi) {
            const int r = (wr * 64 + mi * 32 + frow) * BKt;
            aF[0][mi] = *(const bf16x8*)(sA + r + slot0 * 8);
            aF[1][mi] = *(const bf16x8*)(sA + r + slot1 * 8);
        }
#pragma unroll
        for (int ni = 0; ni < 2; ++ni) {
            const int r = (wc * 64 + ni * 32 + frow) * BKt;
            bF[0][ni] = *(const bf16x8*)(sB + r + slot0 * 8);
            bF[1][ni] = *(const bf16x8*)(sB + r + slot1 * 8);
        }
#pragma unroll
        for (int ks = 0; ks < 2; ++ks)
#pragma unroll
            for (int mi = 0; mi < 2; ++mi)
#pragma unroll
                for (int ni = 0; ni < 2; ++ni)
                    acc[mi][ni] = __builtin_amdgcn_mfma_f32_32x32x16_bf16(
                        aF[ks][mi], bF[ks][ni], acc[mi][ni], 0, 0, 0);
    }

    // Epilogue: 32x32 C/D layout col=lane&31, row=(reg&3)+8*(reg>>2)+4*(lane>>5)
    // [m74/m101-verified]
    const int cl = lane & 31;
    const int rb = 4 * (lane >> 5);
#pragma unroll
    for (int ni = 0; ni < 2; ++ni) {
        const int   c  = n0 + wc * 64 + ni * 32 + cl;
        const float bv = bias[c];
#pragma unroll
        for (int mi = 0; mi < 2; ++mi) {
            const int rowbase = m0 + wr * 64 + mi * 32 + rb;
#pragma unroll
            for (int rg = 0; rg < 16; ++rg) {
                const int row = rowbase + (rg & 3) + 8 * (rg >> 2);
                C[(size_t)row * N + c] = acc[mi][ni][rg] + bv;
            }
        }
    }
}

// ---------------------------------------------------------------------------
extern "C" void kernel_launch(void* const* d_in, const int* in_sizes, int n_in,
                              void* d_out, int out_size, void* d_ws, size_t ws_size,
                              hipStream_t stream) {
    const float* x     = (const float*)d_in[0];   // [8,2048,4096] fp32
    const int*   Wq    = (const int*)d_in[1];     // [64,262144] int32
    const float* scale = (const float*)d_in[2];   // [1,262144]
    const float* zero  = (const float*)d_in[3];   // [1,262144]
    const float* bias  = (const float*)d_in[4];   // [4096]
    float* out = (float*)d_out;                   // [8,2048,4096] fp32

    const size_t wbytes = (size_t)OUT_F * IN_F * 2;   // 33.6 MB bf16 W
    const size_t xbytes = (size_t)MROWS * IN_F * 2;   // 134 MB bf16 x
    if (ws_size < wbytes + xbytes) {
        fprintf(stderr, "kernel_launch: ws_size=%zu < needed %zu — aborting\n",
                ws_size, wbytes + xbytes);
        return;
    }
    __bf16* Wb = (__bf16*)d_ws;
    __bf16* xb = (__bf16*)((char*)d_ws + wbytes);

    dequant_w<<<(OUT_F * IN_F / 4) / 256, 256, 0, stream>>>(Wq, scale, zero, Wb);
    convert_x<<<((size_t)MROWS * IN_F / 8) / 256, 256, 0, stream>>>(x, xb);

    dim3 grid(OUT_F / 128, MROWS / 128);   // (32, 128) = 4096 blocks
    gemm_bt_bias<<<grid, 256, 0, stream>>>(xb, Wb, bias, out);
}